// Round 11
// baseline (404.373 us; speedup 1.0000x reference)
//
#include <hip/hip_runtime.h>
#include <cstddef>

// Multigrid F-cycle advection, 4096^2 f32, T=4 outer iterations.
// R11: R6 structure + k_mid consolidation + LDS-tile-staged SR.
// 4 launches/iteration:
//   1. k_sr_chain : stage 66x130 v tile in LDS (coalesced float4, 1 barrier),
//                   compute 32x64 r1 tile (verbatim R2 unit math) + in-LDS
//                   restrict chain r2,r3,r4,r5 (LDS reused after barrier)
//   2. k_mid      : per-block redundant r5->E6 chain -> local E5/E4/E3 (LDS)
//                   -> writes 64x64 E2 tile (verbatim R8/R10, proven)
//   3. k_up(2048) : E1 = up(E2, r1)  (E1 round-trip cheaper than fusion)
//   4. k_final    : v' = w - smooth(bc(w)), w = v - prolong(E1) (verbatim R2)
// All FP op orders identical to R2/R6 (passing, absmax 3.814697e-06).

constexpr float CW = 0.05f;  // CXW == CYW == DT/DX/2

// e_new = (Pc - smooth_zero_pad(P)) + r, reference rounding order.
__device__ __forceinline__ float up_val(float Pc, float Pu, float Pd, float Pl,
                                        float Pr, float rv) {
  float sm = CW * Pu - CW * Pd + CW * Pl + Pc - CW * Pr;
  return (Pc - sm) + rv;
}

// ---------------------------------------------------------------------------
// k_sr_chain: grid (32, 64) blocks x 256 thr. Block -> 32x64 r1 tile.
// v region: rows 64*by-1 .. 64*by+64 (66, row-clamped), cols 128*bx-1 ..
// 128*bx+128 (130, col-clamped at halos). LDS vls[66][133]: halo-L at col 0,
// interior cols 1..128, halo-R at col 129.
#define SR_STRIDE 133
__global__ __launch_bounds__(256) void k_sr_chain(
    const float* __restrict__ v, float* __restrict__ r1,
    float* __restrict__ r2, float* __restrict__ r3,
    float* __restrict__ r4, float* __restrict__ r5) {
  const int n = 4096;
  __shared__ float smem[66 * SR_STRIDE];  // 35.1 KB; reused by chain phases
  int tid = threadIdx.x;
  int bx = blockIdx.x, by = blockIdx.y;
  int R0 = 64 * by - 1;    // global v row of LDS row 0 (pre-clamp)
  int C0 = 128 * bx;       // global v col of LDS col 1

  // ---- Stage: interior 66 x 128 as float4 (2112 f4, 8.25/thread) ----------
  for (int idx = tid; idx < 66 * 32; idx += 256) {
    int lr = idx >> 5, k = idx & 31;
    int gr = min(max(R0 + lr, 0), n - 1);
    float4 m = *reinterpret_cast<const float4*>(v + (size_t)gr * n + C0 + 4 * k);
    float* d = smem + lr * SR_STRIDE + 1 + 4 * k;
    d[0] = m.x; d[1] = m.y; d[2] = m.z; d[3] = m.w;
  }
  // ---- Stage: column halos (2 x 66 scalars) -------------------------------
  if (tid < 132) {
    int side = tid & 1, lr = tid >> 1;
    int gr = min(max(R0 + lr, 0), n - 1);
    int gc = side ? min(C0 + 128, n - 1) : max(C0 - 1, 0);
    smem[lr * SR_STRIDE + (side ? 129 : 0)] = v[(size_t)gr * n + gc];
  }
  __syncthreads();

  // ---- Phase A: 2x4 r1 outputs per thread from 6x10 LDS window ------------
  // Thread (ty=tid>>4, tx=tid&15): r1 rows 32by+2ty+{0,1}, cols 64bx+4tx+{0..3}
  int tx = tid & 15, ty = tid >> 4;
  float win[6][10];
#pragma unroll
  for (int rr = 0; rr < 6; ++rr) {
    const float* row = smem + (4 * ty + rr) * SR_STRIDE + 8 * tx;
#pragma unroll
    for (int ww = 0; ww < 10; ++ww) win[rr][ww] = row[ww];
  }
  float4 ov[2];
#pragma unroll
  for (int oi = 0; oi < 2; ++oi) {
#pragma unroll
    for (int u = 0; u < 2; ++u) {
#pragma unroll
      for (int oj = 0; oj < 2; ++oj) {
        float s[2][2];
#pragma unroll
        for (int p = 0; p < 2; ++p)
#pragma unroll
          for (int q = 0; q < 2; ++q) {
            int P = 2 * oi + p, Q = 2 * oj + q;
            // verbatim R2: CYW*up - CYW*down + CXW*left + center - CXW*right
            s[p][q] = CW * win[P][4 * u + Q + 1] - CW * win[P + 2][4 * u + Q + 1]
                    + CW * win[P + 1][4 * u + Q] + win[P + 1][4 * u + Q + 1]
                    - CW * win[P + 1][4 * u + Q + 2];
          }
        (&ov[oi].x)[2 * u + oj] =
            0.25f * (((s[0][0] + s[1][0]) + s[0][1]) + s[1][1]);
      }
    }
    *reinterpret_cast<float4*>(
        r1 + (size_t)(32 * by + 2 * ty + oi) * 2048 + 64 * bx + 4 * tx) = ov[oi];
  }
  __syncthreads();  // all vls reads done; reuse smem for chain

  // ---- Chain: r1s (32x65) then r2,r3,r4,r5 (verbatim R6 math) -------------
  float* r1s = smem;                       // [32][65]
  float* r2s = smem + 32 * 65;             // [16][33]
  float* r3s = smem + 32 * 65 + 16 * 33;   // [8][17]
  float* r4s = smem + 32 * 65 + 16 * 33 + 8 * 17;  // [4][9]
#pragma unroll
  for (int oi = 0; oi < 2; ++oi)
#pragma unroll
    for (int cc = 0; cc < 4; ++cc)
      r1s[(2 * ty + oi) * 65 + 4 * tx + cc] = (&ov[oi].x)[cc];
  __syncthreads();

#pragma unroll
  for (int k = 0; k < 2; ++k) {  // r2: 16x32
    int idx = tid + 256 * k;
    int I = idx >> 5, J = idx & 31;
    float val = 0.25f * (((r1s[(2 * I) * 65 + 2 * J] + r1s[(2 * I + 1) * 65 + 2 * J])
                          + r1s[(2 * I) * 65 + 2 * J + 1]) + r1s[(2 * I + 1) * 65 + 2 * J + 1]);
    r2s[I * 33 + J] = val;
    r2[(size_t)(16 * by + I) * 1024 + 32 * bx + J] = val;
  }
  __syncthreads();
  if (tid < 128) {  // r3: 8x16
    int I = tid >> 4, J = tid & 15;
    float val = 0.25f * (((r2s[(2 * I) * 33 + 2 * J] + r2s[(2 * I + 1) * 33 + 2 * J])
                          + r2s[(2 * I) * 33 + 2 * J + 1]) + r2s[(2 * I + 1) * 33 + 2 * J + 1]);
    r3s[I * 17 + J] = val;
    r3[(size_t)(8 * by + I) * 512 + 16 * bx + J] = val;
  }
  __syncthreads();
  if (tid < 32) {  // r4: 4x8
    int I = tid >> 3, J = tid & 7;
    float val = 0.25f * (((r3s[(2 * I) * 17 + 2 * J] + r3s[(2 * I + 1) * 17 + 2 * J])
                          + r3s[(2 * I) * 17 + 2 * J + 1]) + r3s[(2 * I + 1) * 17 + 2 * J + 1]);
    r4s[I * 9 + J] = val;
    r4[(size_t)(4 * by + I) * 256 + 8 * bx + J] = val;
  }
  __syncthreads();
  if (tid < 8) {  // r5: 2x4
    int I = tid >> 2, J = tid & 3;
    float val = 0.25f * (((r4s[(2 * I) * 9 + 2 * J] + r4s[(2 * I + 1) * 9 + 2 * J])
                          + r4s[(2 * I) * 9 + 2 * J + 1]) + r4s[(2 * I + 1) * 9 + 2 * J + 1]);
    r5[(size_t)(2 * by + I) * 128 + 4 * bx + J] = val;
  }
}

// ---------------------------------------------------------------------------
// k_mid: verbatim R8/R10 (proven bit-exact). Per-block redundant coarse chain
// in LDS -> local E5/E4/E3 -> writes 64x64 E2 tile.
__global__ __launch_bounds__(256, 1) void k_mid(
    const float* __restrict__ r5, const float* __restrict__ r4,
    const float* __restrict__ r3, const float* __restrict__ r2,
    float* __restrict__ E2) {
  __shared__ float r5s[128 * 128];
  __shared__ float r6s[64 * 64];
  __shared__ float r7s[32 * 32];
  __shared__ float r8s[16 * 16];
  __shared__ float r9s[8 * 8];
  __shared__ float E8s[16 * 16];
  __shared__ float E7s[32 * 32];
  __shared__ float E6s[64 * 64];
  __shared__ float e5r[10][128];
  __shared__ float e4s[18][20];
  __shared__ float e3s[34][35];
  int tid = threadIdx.x;
  int bx = blockIdx.x, by = blockIdx.y;

  auto up_lds = [&](const float* Ep, const float* rr, int i, int c, int nn) {
    int ss = nn >> 1;
    float Pc = Ep[(i >> 1) * ss + (c >> 1)];
    float Pu = (i > 0)      ? Ep[((i - 1) >> 1) * ss + (c >> 1)] : 0.0f;
    float Pd = (i < nn - 1) ? Ep[((i + 1) >> 1) * ss + (c >> 1)] : 0.0f;
    float Pl = (c > 0)      ? Ep[(i >> 1) * ss + ((c - 1) >> 1)] : 0.0f;
    float Pr = (c < nn - 1) ? Ep[(i >> 1) * ss + ((c + 1) >> 1)] : 0.0f;
    return up_val(Pc, Pu, Pd, Pl, Pr, rr[i * nn + c]);
  };

  for (int idx = tid; idx < 4096; idx += 256)
    reinterpret_cast<float4*>(r5s)[idx] = reinterpret_cast<const float4*>(r5)[idx];
  __syncthreads();
  for (int idx = tid; idx < 64 * 64; idx += 256) {
    int I = idx >> 6, J = idx & 63;
    float a = r5s[(2 * I) * 128 + 2 * J],     b = r5s[(2 * I + 1) * 128 + 2 * J];
    float c = r5s[(2 * I) * 128 + 2 * J + 1], d = r5s[(2 * I + 1) * 128 + 2 * J + 1];
    r6s[idx] = 0.25f * (((a + b) + c) + d);
  }
  __syncthreads();
  for (int idx = tid; idx < 32 * 32; idx += 256) {
    int I = idx >> 5, J = idx & 31;
    float a = r6s[(2 * I) * 64 + 2 * J],     b = r6s[(2 * I + 1) * 64 + 2 * J];
    float c = r6s[(2 * I) * 64 + 2 * J + 1], d = r6s[(2 * I + 1) * 64 + 2 * J + 1];
    r7s[idx] = 0.25f * (((a + b) + c) + d);
  }
  __syncthreads();
  if (tid < 16 * 16) {
    int I = tid >> 4, J = tid & 15;
    float a = r7s[(2 * I) * 32 + 2 * J],     b = r7s[(2 * I + 1) * 32 + 2 * J];
    float c = r7s[(2 * I) * 32 + 2 * J + 1], d = r7s[(2 * I + 1) * 32 + 2 * J + 1];
    r8s[tid] = 0.25f * (((a + b) + c) + d);
  }
  __syncthreads();
  if (tid < 8 * 8) {
    int I = tid >> 3, J = tid & 7;
    float a = r8s[(2 * I) * 16 + 2 * J],     b = r8s[(2 * I + 1) * 16 + 2 * J];
    float c = r8s[(2 * I) * 16 + 2 * J + 1], d = r8s[(2 * I + 1) * 16 + 2 * J + 1];
    r9s[tid] = 0.25f * (((a + b) + c) + d);
  }
  __syncthreads();
  if (tid < 16 * 16)
    E8s[tid] = up_lds(r9s, r8s, tid >> 4, tid & 15, 16);
  __syncthreads();
  if (tid < 32 * 32)
    E7s[tid] = up_lds(E8s, r7s, tid >> 5, tid & 31, 32);
  __syncthreads();
  for (int idx = tid; idx < 64 * 64; idx += 256)
    E6s[idx] = up_lds(E7s, r6s, idx >> 6, idx & 63, 64);
  __syncthreads();
  for (int idx = tid; idx < 10 * 128; idx += 256) {
    int t = idx >> 7, c = idx & 127;
    int i = min(max(8 * by - 1 + t, 0), 127);
    e5r[t][c] = up_lds(E6s, r5s, i, c, 128);
  }
  __syncthreads();
  for (int idx = tid; idx < 18 * 18; idx += 256) {
    int er = idx / 18, ec = idx % 18;
    int ga = 16 * by - 1 + er, gb = 16 * bx - 1 + ec;
    if (ga >= 0 && ga < 256 && gb >= 0 && gb < 256) {
      float Pc = e5r[(ga >> 1) - (8 * by - 1)][gb >> 1];
      float Pu = (ga > 0)   ? e5r[((ga - 1) >> 1) - (8 * by - 1)][gb >> 1] : 0.0f;
      float Pd = (ga < 255) ? e5r[((ga + 1) >> 1) - (8 * by - 1)][gb >> 1] : 0.0f;
      float Pl = (gb > 0)   ? e5r[(ga >> 1) - (8 * by - 1)][(gb - 1) >> 1] : 0.0f;
      float Pr = (gb < 255) ? e5r[(ga >> 1) - (8 * by - 1)][(gb + 1) >> 1] : 0.0f;
      e4s[er][ec] = up_val(Pc, Pu, Pd, Pl, Pr, r4[(size_t)ga * 256 + gb]);
    }
  }
  __syncthreads();
  for (int idx = tid; idx < 34 * 34; idx += 256) {
    int er = idx / 34, ec = idx % 34;
    int gr = 32 * by - 1 + er, gc = 32 * bx - 1 + ec;
    float val = 0.0f;
    if (gr >= 0 && gr < 512 && gc >= 0 && gc < 512) {
      int e4r0 = 16 * by - 1, e4c0 = 16 * bx - 1;
      float Pc = e4s[(gr >> 1) - e4r0][(gc >> 1) - e4c0];
      float Pu = (gr > 0)   ? e4s[((gr - 1) >> 1) - e4r0][(gc >> 1) - e4c0] : 0.0f;
      float Pd = (gr < 511) ? e4s[((gr + 1) >> 1) - e4r0][(gc >> 1) - e4c0] : 0.0f;
      float Pl = (gc > 0)   ? e4s[(gr >> 1) - e4r0][((gc - 1) >> 1) - e4c0] : 0.0f;
      float Pr = (gc < 511) ? e4s[(gr >> 1) - e4r0][((gc + 1) >> 1) - e4c0] : 0.0f;
      val = up_val(Pc, Pu, Pd, Pl, Pr, r3[(size_t)gr * 512 + gc]);
    }
    e3s[er][ec] = val;
  }
  __syncthreads();
  int br0 = 32 * by - 1, bc0 = 32 * bx - 1;
#pragma unroll
  for (int k = 0; k < 4; ++k) {
    int u = tid + 256 * k;
    int rr = u >> 4, f = u & 15;
    int gR = 64 * by + rr;
    int gC = 64 * bx + 4 * f;
    int rc = (gR >> 1) - br0;
    int ru = ((gR - 1) >> 1) - br0;
    int rd = ((gR + 1) >> 1) - br0;
    float4 rv = *reinterpret_cast<const float4*>(r2 + (size_t)gR * 1024 + gC);
    float4 o;
#pragma unroll
    for (int q = 0; q < 4; ++q) {
      int c = gC + q;
      int lc = (c >> 1) - bc0;
      float Pc = e3s[rc][lc];
      float Pu = (gR > 0)    ? e3s[ru][lc] : 0.0f;
      float Pd = (gR < 1023) ? e3s[rd][lc] : 0.0f;
      float Pl = (c > 0)     ? e3s[rc][((c - 1) >> 1) - bc0] : 0.0f;
      float Pr = (c < 1023)  ? e3s[rc][((c + 1) >> 1) - bc0] : 0.0f;
      (&o.x)[q] = up_val(Pc, Pu, Pd, Pl, Pr, (&rv.x)[q]);
    }
    *reinterpret_cast<float4*>(E2 + (size_t)gR * 1024 + gC) = o;
  }
}

// ---------------------------------------------------------------------------
// k_up (n=2048): E1 = up(E2, r1). Verbatim R2/R6.
__global__ __launch_bounds__(256) void k_up(
    const float* __restrict__ Ep, const float* __restrict__ r,
    float* __restrict__ Eo, int n) {
  int s = n >> 1;
  int j = blockIdx.x * blockDim.x + threadIdx.x;
  int i = blockIdx.y * blockDim.y + threadIdx.y;
  if (i >= s || j >= (n >> 2)) return;
  const float* ec = Ep + (size_t)i * s + 2 * j;
  float epc0 = ec[0], epc1 = ec[1];
  float epl = (j > 0) ? ec[-1] : 0.0f;
  float epr = (2 * j + 2 < s) ? ec[2] : 0.0f;
  float epu0 = 0.0f, epu1 = 0.0f, epd0 = 0.0f, epd1 = 0.0f;
  if (i > 0)     { epu0 = ec[-s]; epu1 = ec[-s + 1]; }
  if (i < s - 1) { epd0 = ec[s];  epd1 = ec[s + 1]; }
  {
    float4 rv = *reinterpret_cast<const float4*>(r + (size_t)(2 * i) * n + 4 * j);
    float4 o;
    o.x = up_val(epc0, epu0, epc0, epl,  epc0, rv.x);
    o.y = up_val(epc0, epu0, epc0, epc0, epc1, rv.y);
    o.z = up_val(epc1, epu1, epc1, epc0, epc1, rv.z);
    o.w = up_val(epc1, epu1, epc1, epc1, epr,  rv.w);
    *reinterpret_cast<float4*>(Eo + (size_t)(2 * i) * n + 4 * j) = o;
  }
  {
    float4 rv = *reinterpret_cast<const float4*>(r + (size_t)(2 * i + 1) * n + 4 * j);
    float4 o;
    o.x = up_val(epc0, epc0, epd0, epl,  epc0, rv.x);
    o.y = up_val(epc0, epc0, epd0, epc0, epc1, rv.y);
    o.z = up_val(epc1, epc1, epd1, epc0, epc1, rv.z);
    o.w = up_val(epc1, epc1, epd1, epc1, epr,  rv.w);
    *reinterpret_cast<float4*>(Eo + (size_t)(2 * i + 1) * n + 4 * j) = o;
  }
}

// ---------------------------------------------------------------------------
// out = w - smooth(bc(w)), w = v - prolong(E1).  (verbatim R2/R6)
__global__ __launch_bounds__(256) void k_final(
    const float* __restrict__ v, const float* __restrict__ E1,
    float* __restrict__ out) {
  const int n = 4096, h = 2048;
  int J = blockIdx.x * blockDim.x + threadIdx.x;
  int i = blockIdx.y * blockDim.y + threadIdx.y;
  int c0 = 4 * J;
  int cl = max(c0 - 1, 0), cr = min(c0 + 4, n - 1);
  int ecl = cl >> 1, ecr = cr >> 1;

  float e[3][4];
  int ers0 = max(2 * i - 1, 0) >> 1;
  int ers2 = min(2 * i + 2, n - 1) >> 1;
  const int ers[3] = {ers0, i, ers2};
#pragma unroll
  for (int t = 0; t < 3; ++t) {
    const float* erow = E1 + (size_t)ers[t] * h;
    e[t][0] = erow[ecl];
    e[t][1] = erow[2 * J];
    e[t][2] = erow[2 * J + 1];
    e[t][3] = erow[ecr];
  }

  float w[4][6];
  const int tmap[4] = {0, 1, 1, 2};
#pragma unroll
  for (int rr = 0; rr < 4; ++rr) {
    int R = min(max(2 * i - 1 + rr, 0), n - 1);
    int t = tmap[rr];
    const float* vrow = v + (size_t)R * n;
    float4 m = *reinterpret_cast<const float4*>(vrow + c0);
    w[rr][0] = vrow[cl] - e[t][0];
    w[rr][1] = m.x - e[t][1];
    w[rr][2] = m.y - e[t][1];
    w[rr][3] = m.z - e[t][2];
    w[rr][4] = m.w - e[t][2];
    w[rr][5] = vrow[cr] - e[t][3];
  }
#pragma unroll
  for (int a = 0; a < 2; ++a) {
    float4 o;
#pragma unroll
    for (int qq = 0; qq < 4; ++qq) {
      float ce = w[a + 1][qq + 1];
      float sm = CW * w[a][qq + 1] - CW * w[a + 2][qq + 1]
               + CW * w[a + 1][qq] + ce - CW * w[a + 1][qq + 2];
      (&o.x)[qq] = ce - sm;
    }
    *reinterpret_cast<float4*>(out + (size_t)(2 * i + a) * n + c0) = o;
  }
}

// ---------------------------------------------------------------------------
extern "C" void kernel_launch(void* const* d_in, const int* in_sizes, int n_in,
                              void* d_out, int out_size, void* d_ws, size_t ws_size,
                              hipStream_t stream) {
  (void)in_sizes; (void)n_in; (void)out_size;
  float* u = (float*)d_in[0];
  float* out = (float*)d_out;
  char* ws = (char*)d_ws;

  size_t off = 0;
  auto alloc = [&](size_t elems) {
    float* p = (float*)(ws + off);
    off += (elems * sizeof(float) + 255) & ~(size_t)255;
    return p;
  };
  float* r1 = alloc(2048 * 2048);
  float* r2 = alloc(1024 * 1024);
  float* r3 = alloc(512 * 512);
  float* r4 = alloc(256 * 256);
  float* r5 = alloc(128 * 128);
  float* E2 = alloc(1024 * 1024);
  float* E1 = alloc(2048 * 2048);
  size_t pool = off;
  const size_t VB = (size_t)4096 * 4096 * sizeof(float);
  bool big = ws_size >= pool + VB;
  float* vws = (float*)(ws + pool);

  dim3 b(64, 4);
  auto iterate = [&](const float* vin, float* vout) {
    k_sr_chain<<<dim3(32, 64), 256, 0, stream>>>(vin, r1, r2, r3, r4, r5);
    k_mid<<<dim3(16, 16), 256, 0, stream>>>(r5, r4, r3, r2, E2);
    k_up<<<dim3(8, 256), b, 0, stream>>>(E2, r1, E1, 2048);
    k_final<<<dim3(16, 512), b, 0, stream>>>(vin, E1, vout);
  };

  if (big) {
    iterate(u, vws);
    iterate(vws, out);
    iterate(out, vws);
    iterate(vws, out);
  } else {
    iterate(u, out);
    iterate(out, u);
    iterate(u, out);
    iterate(out, u);
    hipMemcpyAsync(out, u, VB, hipMemcpyDeviceToDevice, stream);
  }
}